// Round 5
// baseline (226.101 us; speedup 1.0000x reference)
//
#include <hip/hip_runtime.h>

// Problem constants
#define BATCH 32
#define CCH 3
#define HW_TEX (512 * 512)
#define N_TEX (HW_TEX * CCH)          // 786432 per-sample flat texture (channels-last)
#define OH 128
#define OW 64
#define P_OUT (OH * OW)               // 8192
#define M_OUT (P_OUT * CCH)           // 24576 rows per sample (96 KB as f32)
#define NNZ 98304
#define OUT_ELEMS (BATCH * M_OUT)     // 786432

#define WS32 ((size_t)32 * 32 * M_OUT * 4)   // 96 MiB  (32 segs x 32 samples)
#define WS8  ((size_t)32 * 8  * M_OUT * 4)   // 25.2 MB

// ---------------- NSEG=32 XCD-resident scan ---------------------------------
// grid 1024, 768 threads, 96 KB LDS -> 1 block/CU -> 4 sequential rounds.
// xcd = blk%8 (hw round-robin), sample = round*8 + xcd: in each round, all
// 32 CUs of an XCD hit ONE sample's 3.1 MB x slab -> gathers are L2 hits.
#define B32 768
__global__ __launch_bounds__(B32) void scan32_kernel(
    const float* __restrict__ x,
    const int*   __restrict__ rows,
    const int*   __restrict__ cols,
    const float* __restrict__ vals,
    float* __restrict__ partial) {
    __shared__ __align__(16) float acc[M_OUT];

    const int blk = blockIdx.x;
    const int xcd = blk & 7;
    const int seg = (blk >> 3) & 31;
    const int rnd = blk >> 8;
    const int s   = rnd * 8 + xcd;
    const int t   = threadIdx.x;

    float4* acc4 = reinterpret_cast<float4*>(acc);
#pragma unroll
    for (int j = 0; j < M_OUT / 4 / B32; ++j)     // 8 per thread
        acc4[t + j * B32] = make_float4(0.f, 0.f, 0.f, 0.f);
    __syncthreads();

    // 3072 nnz per block = 768 threads x 1 int4 each
    const size_t off = (size_t)s * NNZ + (size_t)seg * (NNZ / 32);
    int4   r = reinterpret_cast<const int4*>(rows + off)[t];
    int4   c = reinterpret_cast<const int4*>(cols + off)[t];
    float4 v = reinterpret_cast<const float4*>(vals + off)[t];
    const float* xs = x + (size_t)s * N_TEX;

    float g0 = xs[(c.x % CCH) * HW_TEX + c.x / CCH];
    float g1 = xs[(c.y % CCH) * HW_TEX + c.y / CCH];
    float g2 = xs[(c.z % CCH) * HW_TEX + c.z / CCH];
    float g3 = xs[(c.w % CCH) * HW_TEX + c.w / CCH];

    atomicAdd(&acc[r.x], v.x * g0);
    atomicAdd(&acc[r.y], v.y * g1);
    atomicAdd(&acc[r.z], v.z * g2);
    atomicAdd(&acc[r.w], v.w * g3);
    __syncthreads();

    float4* pp = reinterpret_cast<float4*>(partial + (size_t)(seg * 32 + s) * M_OUT);
#pragma unroll
    for (int j = 0; j < M_OUT / 4 / B32; ++j)
        pp[t + j * B32] = acc4[t + j * B32];
}

// ---------------- NSEG=8 scan (R4 path, fallback) ---------------------------
#define BLOCK 1024
template <int NSEG>
__global__ __launch_bounds__(BLOCK) void scan_full_kernel(
    const float* __restrict__ x,
    const int*   __restrict__ rows,
    const int*   __restrict__ cols,
    const float* __restrict__ vals,
    float* __restrict__ partial) {
    __shared__ __align__(16) float acc[M_OUT];
    const int blk = blockIdx.x;
    const int s   = blk & 31;
    const int seg = blk >> 5;
    const int t   = threadIdx.x;
    float4* acc4 = reinterpret_cast<float4*>(acc);
#pragma unroll
    for (int j = 0; j < M_OUT / 4 / BLOCK; ++j)
        acc4[t + j * BLOCK] = make_float4(0.f, 0.f, 0.f, 0.f);
    __syncthreads();
    constexpr int SEGN = NNZ / NSEG;
    const size_t  off  = (size_t)s * NNZ + (size_t)seg * SEGN;
    const int4*   r4 = reinterpret_cast<const int4*>(rows + off);
    const int4*   c4 = reinterpret_cast<const int4*>(cols + off);
    const float4* v4 = reinterpret_cast<const float4*>(vals + off);
    const float*  xs = x + (size_t)s * N_TEX;
#pragma unroll
    for (int j = 0; j < SEGN / (BLOCK * 4); ++j) {
        int4   r = r4[j * BLOCK + t];
        int4   c = c4[j * BLOCK + t];
        float4 v = v4[j * BLOCK + t];
        float g0 = xs[(c.x % CCH) * HW_TEX + c.x / CCH];
        float g1 = xs[(c.y % CCH) * HW_TEX + c.y / CCH];
        float g2 = xs[(c.z % CCH) * HW_TEX + c.z / CCH];
        float g3 = xs[(c.w % CCH) * HW_TEX + c.w / CCH];
        atomicAdd(&acc[r.x], v.x * g0);
        atomicAdd(&acc[r.y], v.y * g1);
        atomicAdd(&acc[r.z], v.z * g2);
        atomicAdd(&acc[r.w], v.w * g3);
    }
    __syncthreads();
    float4* pp = reinterpret_cast<float4*>(partial + (size_t)(seg * 32 + s) * M_OUT);
#pragma unroll
    for (int j = 0; j < M_OUT / 4 / BLOCK; ++j)
        pp[t + j * BLOCK] = acc4[t + j * BLOCK];
}

// ---------------- Reduce: sum nseg partials, CHW transform, mask copy -------
// partial layout: partial[(seg*32 + s)*M + rcl]; one thread = 4 consecutive rcl.
__global__ __launch_bounds__(256) void reduce_kernel(
    const float* __restrict__ partial,
    const float* __restrict__ mask,
    float* __restrict__ out, int nseg) {
    int tid = blockIdx.x * 256 + threadIdx.x;         // over OUT_ELEMS/4
    if (tid >= OUT_ELEMS / 4) return;
    int s    = tid / (M_OUT / 4);
    int rcl4 = (tid % (M_OUT / 4)) * 4;               // first of 4 rows

    const float4* pp = reinterpret_cast<const float4*>(
        partial + (size_t)s * M_OUT + rcl4);
    const size_t stride4 = (size_t)32 * M_OUT / 4;    // seg stride in float4s
    float4 sum = make_float4(0.f, 0.f, 0.f, 0.f);
    for (int seg = 0; seg < nseg; ++seg) {
        float4 p = pp[(size_t)seg * stride4];
        sum.x += p.x; sum.y += p.y; sum.z += p.z; sum.w += p.w;
    }
    // channels-last rcl -> CHW
    float* ob = out + (size_t)s * M_OUT;
    ob[(rcl4 + 0) % CCH * P_OUT + (rcl4 + 0) / CCH] = sum.x;
    ob[(rcl4 + 1) % CCH * P_OUT + (rcl4 + 1) / CCH] = sum.y;
    ob[(rcl4 + 2) % CCH * P_OUT + (rcl4 + 2) / CCH] = sum.z;
    ob[(rcl4 + 3) % CCH * P_OUT + (rcl4 + 3) / CCH] = sum.w;
    // mask passthrough (same layout both sides)
    reinterpret_cast<float4*>(out + OUT_ELEMS)[tid] =
        reinterpret_cast<const float4*>(mask)[tid];
}

// ---------------- Final fallback (R2): no workspace -------------------------
#define CHUNKS 8
#define RPC (M_OUT / CHUNKS)
__global__ __launch_bounds__(BLOCK) void spmm_chunk_kernel(
    const float* __restrict__ x,
    const int*   __restrict__ rows,
    const int*   __restrict__ cols,
    const float* __restrict__ vals,
    const float* __restrict__ mask,
    float* __restrict__ out) {
    __shared__ float acc[RPC];
    const int blk = blockIdx.x;
    const int s   = blk / CHUNKS;
    const int c   = blk % CHUNKS;
    const int t   = threadIdx.x;
    const int rbase = c * RPC;
#pragma unroll
    for (int j = 0; j < RPC / BLOCK; ++j) acc[t + j * BLOCK] = 0.0f;
    __syncthreads();
    const int*   rs = rows + (size_t)s * NNZ;
    const int*   cs = cols + (size_t)s * NNZ;
    const float* vs = vals + (size_t)s * NNZ;
    const float* xs = x    + (size_t)s * N_TEX;
#pragma unroll 4
    for (int i = t; i < NNZ; i += BLOCK) {
        int r = rs[i];
        unsigned lr = (unsigned)(r - rbase);
        if (lr < (unsigned)RPC) {
            int   col = cs[i];
            float v   = vs[i];
            atomicAdd(&acc[lr], v * xs[(col % CCH) * HW_TEX + col / CCH]);
        }
    }
    __syncthreads();
    const size_t outbase = (size_t)s * M_OUT;
#pragma unroll
    for (int ch = 0; ch < CCH; ++ch)
        out[outbase + (size_t)ch * P_OUT + c * (P_OUT / CHUNKS) + t] = acc[t * CCH + ch];
    {
        float* mout = out + OUT_ELEMS;
        const int base = blk * RPC;
#pragma unroll
        for (int j = 0; j < RPC / BLOCK; ++j)
            mout[base + j * BLOCK + t] = mask[base + j * BLOCK + t];
    }
}

extern "C" void kernel_launch(void* const* d_in, const int* in_sizes, int n_in,
                              void* d_out, int out_size, void* d_ws, size_t ws_size,
                              hipStream_t stream) {
    const float* x    = (const float*)d_in[0];
    const int*   rows = (const int*)  d_in[1];
    const int*   cols = (const int*)  d_in[2];
    const float* vals = (const float*)d_in[3];
    const float* mask = (const float*)d_in[4];
    float* out = (float*)d_out;
    int rgrid = (OUT_ELEMS / 4 + 255) / 256;   // 768

    if (ws_size >= WS32) {
        float* partial = (float*)d_ws;
        scan32_kernel<<<1024, B32, 0, stream>>>(x, rows, cols, vals, partial);
        reduce_kernel<<<rgrid, 256, 0, stream>>>(partial, mask, out, 32);
    } else if (ws_size >= WS8) {
        float* partial = (float*)d_ws;
        scan_full_kernel<8><<<32 * 8, BLOCK, 0, stream>>>(x, rows, cols, vals, partial);
        reduce_kernel<<<rgrid, 256, 0, stream>>>(partial, mask, out, 8);
    } else {
        spmm_chunk_kernel<<<BATCH * CHUNKS, BLOCK, 0, stream>>>(x, rows, cols, vals, mask, out);
    }
}

// Round 6
// 206.293 us; speedup vs baseline: 1.0960x; 1.0960x over previous
//
#include <hip/hip_runtime.h>

// Problem constants
#define BATCH 32
#define CCH 3
#define HW_TEX (512 * 512)
#define N_TEX (HW_TEX * CCH)          // 786432 per-sample flat texture (channels-last)
#define OH 128
#define OW 64
#define P_OUT (OH * OW)               // 8192
#define M_OUT (P_OUT * CCH)           // 24576 rows per sample (channels-last)
#define NNZ 98304
#define OUT_ELEMS (BATCH * M_OUT)     // 786432

// New path geometry
#define NCH 4                          // row chunks per sample
#define RPCH (M_OUT / NCH)             // 6144 rows -> 24 KB LDS
#define NE 8                           // nnz eighths
#define SEGE (NNZ / NE)                // 12288 nnz per block-round
#define TB 1024                        // threads -> 12 nnz/thread/round
#define NROUND 4                       // samples per XCD

#define WS_NEED ((size_t)BATCH * NCH * NE * RPCH * 4)   // 25.17 MB
#define WS8     ((size_t)32 * 8 * M_OUT * 4)            // 25.17 MB (R4 layout)

// ---------- scan: chunk-specialized, MLP-batched, XCD-sample-phased ----------
// blk: xcd = blk&7, slot = blk>>3 -> chunk c = slot&3, eighth e = slot>>2.
// Round rnd: all 32 blocks of an XCD scan sample s = rnd*8+xcd (L2-resident).
__global__ __launch_bounds__(TB) void scan_chunk_kernel(
    const float* __restrict__ x,
    const int*   __restrict__ rows,
    const int*   __restrict__ cols,
    const float* __restrict__ vals,
    float* __restrict__ partial) {
    __shared__ __align__(16) float acc[RPCH];

    const int blk  = blockIdx.x;
    const int xcd  = blk & 7;
    const int slot = blk >> 3;
    const int c    = slot & (NCH - 1);
    const int e    = slot >> 2;
    const int t    = threadIdx.x;
    const int rbase = c * RPCH;

    for (int rnd = 0; rnd < NROUND; ++rnd) {
        const int s = rnd * 8 + xcd;

        // zero 24 KB: 3 x float2 per thread
        float2* acc2 = reinterpret_cast<float2*>(acc);
#pragma unroll
        for (int j = 0; j < RPCH / 2 / TB; ++j)
            acc2[t + j * TB] = make_float2(0.f, 0.f);
        __syncthreads();

        const size_t off = (size_t)s * NNZ + (size_t)e * SEGE;
        const int4*   r4 = reinterpret_cast<const int4*>(rows + off);
        const int4*   c4 = reinterpret_cast<const int4*>(cols + off);
        const float4* v4 = reinterpret_cast<const float4*>(vals + off);
        const float*  xs = x + (size_t)s * N_TEX;

        // Unconditional batched index loads: 9 int4/float4 -> full MLP
        int4 r[3], cc[3]; float4 v[3];
#pragma unroll
        for (int j = 0; j < 3; ++j) {
            r[j]  = r4[j * TB + t];
            cc[j] = c4[j * TB + t];
            v[j]  = v4[j * TB + t];
        }

#pragma unroll
        for (int j = 0; j < 3; ++j) {
            int  ri[4] = {r[j].x, r[j].y, r[j].z, r[j].w};
            int  ci[4] = {cc[j].x, cc[j].y, cc[j].z, cc[j].w};
            float vi[4] = {v[j].x, v[j].y, v[j].z, v[j].w};
#pragma unroll
            for (int k = 0; k < 4; ++k) {
                unsigned lr = (unsigned)(ri[k] - rbase);
                bool in = lr < (unsigned)RPCH;
                // safe unconditional gather: inactive lanes hit xs[0] (1 line)
                int gi = in ? ((ci[k] % CCH) * HW_TEX + ci[k] / CCH) : 0;
                float g = xs[gi];
                if (in) atomicAdd(&acc[lr], vi[k] * g);
            }
        }
        __syncthreads();

        // dump 24 KB partial, coalesced float2
        float2* pp = reinterpret_cast<float2*>(
            partial + (((size_t)s * NCH + c) * NE + e) * RPCH);
#pragma unroll
        for (int j = 0; j < RPCH / 2 / TB; ++j)
            pp[t + j * TB] = acc2[t + j * TB];
        __syncthreads();
    }
}

// ---------- reduce: sum NE partials per (s,chunk,row), CHW transform, mask --
__global__ __launch_bounds__(256) void reduce_chunk_kernel(
    const float* __restrict__ partial,
    const float* __restrict__ mask,
    float* __restrict__ out) {
    int tid = blockIdx.x * 256 + threadIdx.x;       // over OUT_ELEMS/4
    if (tid >= OUT_ELEMS / 4) return;
    int s    = tid / (M_OUT / 4);
    int rcl4 = (tid % (M_OUT / 4)) * 4;             // 4 consecutive channels-last rows
    int c    = rcl4 / RPCH;                         // chunk (rcl4%RPCH in same chunk: 6144%4==0)
    int lr4  = rcl4 % RPCH;

    const float4* pp = reinterpret_cast<const float4*>(
        partial + (((size_t)s * NCH + c) * NE) * RPCH + lr4);
    float4 sum = make_float4(0.f, 0.f, 0.f, 0.f);
#pragma unroll
    for (int e = 0; e < NE; ++e) {
        float4 p = pp[(size_t)e * (RPCH / 4)];
        sum.x += p.x; sum.y += p.y; sum.z += p.z; sum.w += p.w;
    }
    float* ob = out + (size_t)s * M_OUT;
    ob[(rcl4 + 0) % CCH * P_OUT + (rcl4 + 0) / CCH] = sum.x;
    ob[(rcl4 + 1) % CCH * P_OUT + (rcl4 + 1) / CCH] = sum.y;
    ob[(rcl4 + 2) % CCH * P_OUT + (rcl4 + 2) / CCH] = sum.z;
    ob[(rcl4 + 3) % CCH * P_OUT + (rcl4 + 3) / CCH] = sum.w;
    reinterpret_cast<float4*>(out + OUT_ELEMS)[tid] =
        reinterpret_cast<const float4*>(mask)[tid];
}

// ---------- fallback (R2): no workspace needed ------------------------------
#define CHUNKS 8
#define RPC (M_OUT / CHUNKS)
#define BLOCK 1024
__global__ __launch_bounds__(BLOCK) void spmm_chunk_kernel(
    const float* __restrict__ x,
    const int*   __restrict__ rows,
    const int*   __restrict__ cols,
    const float* __restrict__ vals,
    const float* __restrict__ mask,
    float* __restrict__ out) {
    __shared__ float acc[RPC];
    const int blk = blockIdx.x;
    const int s   = blk / CHUNKS;
    const int c   = blk % CHUNKS;
    const int t   = threadIdx.x;
    const int rbase = c * RPC;
#pragma unroll
    for (int j = 0; j < RPC / BLOCK; ++j) acc[t + j * BLOCK] = 0.0f;
    __syncthreads();
    const int*   rs = rows + (size_t)s * NNZ;
    const int*   cs = cols + (size_t)s * NNZ;
    const float* vs = vals + (size_t)s * NNZ;
    const float* xs = x    + (size_t)s * N_TEX;
#pragma unroll 4
    for (int i = t; i < NNZ; i += BLOCK) {
        int r = rs[i];
        unsigned lr = (unsigned)(r - rbase);
        if (lr < (unsigned)RPC) {
            int   col = cs[i];
            float v   = vs[i];
            atomicAdd(&acc[lr], v * xs[(col % CCH) * HW_TEX + col / CCH]);
        }
    }
    __syncthreads();
    const size_t outbase = (size_t)s * M_OUT;
#pragma unroll
    for (int ch = 0; ch < CCH; ++ch)
        out[outbase + (size_t)ch * P_OUT + c * (P_OUT / CHUNKS) + t] = acc[t * CCH + ch];
    {
        float* mout = out + OUT_ELEMS;
        const int base = blk * RPC;
#pragma unroll
        for (int j = 0; j < RPC / BLOCK; ++j)
            mout[base + j * BLOCK + t] = mask[base + j * BLOCK + t];
    }
}

extern "C" void kernel_launch(void* const* d_in, const int* in_sizes, int n_in,
                              void* d_out, int out_size, void* d_ws, size_t ws_size,
                              hipStream_t stream) {
    const float* x    = (const float*)d_in[0];
    const int*   rows = (const int*)  d_in[1];
    const int*   cols = (const int*)  d_in[2];
    const float* vals = (const float*)d_in[3];
    const float* mask = (const float*)d_in[4];
    float* out = (float*)d_out;
    int rgrid = (OUT_ELEMS / 4 + 255) / 256;   // 768

    if (ws_size >= WS_NEED) {
        float* partial = (float*)d_ws;
        scan_chunk_kernel<<<256, TB, 0, stream>>>(x, rows, cols, vals, partial);
        reduce_chunk_kernel<<<rgrid, 256, 0, stream>>>(partial, mask, out);
    } else {
        spmm_chunk_kernel<<<BATCH * CHUNKS, BLOCK, 0, stream>>>(x, rows, cols, vals, mask, out);
    }
}